// Round 10
// baseline (221.923 us; speedup 1.0000x reference)
//
#include <hip/hip_runtime.h>
#include <hip/hip_cooperative_groups.h>
#include <math.h>

#define B_TOTAL 16384
#define F_TOTAL 256
#define H1 32
#define H2 16
#define FPB 8      // features per block -> 32 feature groups
#define RPB 512    // rows per block (4 waves x 128 rows) -> 32 row blocks
#define NG 32      // feature groups

typedef _Float16 f16;
typedef __attribute__((ext_vector_type(2))) _Float16 f16x2;
typedef __attribute__((ext_vector_type(8))) _Float16 f16x8;
typedef __attribute__((ext_vector_type(4))) float floatx4;

union F8 { uint4 u; f16x2 h2[4]; f16x8 h8; };
union U1 { unsigned u; f16x2 h; };
union HU { f16 h; unsigned short u; };

namespace cg = cooperative_groups;

// Phase 1: inline pack (per-block, redundant but L2-trivial) + K-loop +
// agent-scope partial stores. Math path identical to rounds 7-9 (verified).
__device__ __forceinline__ void nam_phase1(
    const float* __restrict__ x,   const float* __restrict__ W1,
    const float* __restrict__ b1,  const float* __restrict__ W2,
    const float* __restrict__ b2,  const float* __restrict__ W3,
    const float* __restrict__ b3,  float* __restrict__ part)
{
    __shared__ uint4 fB[FPB * 128];             // 16 KB: hi/lo B-frags
    __shared__ unsigned short xs_h[FPB * RPB];  // 8 KB: x as f16 bits
    __shared__ uint4 w1b1s[FPB * 4 * 2];        // 1 KB
    __shared__ float2 bws[FPB * 16];            // 1 KB
    __shared__ float b3s[FPB];

    const int t = threadIdx.x;
    const int lane = t & 63;
    const int wave = t >> 6;
    const int n = lane & 15, q = lane >> 4;
    const int b0 = blockIdx.x * RPB;
    const int f0 = blockIdx.y * FPB;

    // ---- inline pack: wave w packs features w*2, w*2+1 ----
    #pragma unroll
    for (int k = 0; k < 2; ++k) {
        const int fi = wave * 2 + k;
        const int f = f0 + fi;
        F8 H, L;
        #pragma unroll
        for (int j = 0; j < 8; ++j) {
            float w = W2[(size_t)f * (H1 * H2) + (q * 8 + j) * H2 + n];
            f16 hi = (f16)w;
            H.h8[j] = hi;
            L.h8[j] = (f16)(w - (float)hi);
        }
        fB[fi * 128 + lane] = H.u;
        fB[fi * 128 + 64 + lane] = L.u;
        if (n == 0) {
            F8 A, Bb;
            #pragma unroll
            for (int j = 0; j < 8; ++j) {
                A.h8[j]  = (f16)W1[(size_t)f * H1 + q * 8 + j];
                Bb.h8[j] = (f16)b1[(size_t)f * H1 + q * 8 + j];
            }
            w1b1s[(fi * 4 + q) * 2]     = A.u;
            w1b1s[(fi * 4 + q) * 2 + 1] = Bb.u;
        }
        if (q == 0) {
            float2 e;
            e.x = b2[(size_t)f * H2 + n];
            e.y = W3[(size_t)f * H2 + n];
            bws[fi * 16 + n] = e;
        }
        if (lane == 0) b3s[fi] = b3[f];
    }
    // ---- stage x rows t and t+256 as f16 bits (cvt here; bit-identical) ----
    #pragma unroll
    for (int h = 0; h < 2; ++h) {
        const int rr = t + h * 256;
        const float4* xr = (const float4*)(x + (size_t)(b0 + rr) * F_TOTAL + f0);
        #pragma unroll
        for (int i = 0; i < 2; ++i) {
            float4 v = xr[i];
            HU a, b, c, d;
            a.h = (f16)v.x; b.h = (f16)v.y; c.h = (f16)v.z; d.h = (f16)v.w;
            xs_h[(i * 4 + 0) * RPB + rr] = a.u;
            xs_h[(i * 4 + 1) * RPB + rr] = b.u;
            xs_h[(i * 4 + 2) * RPB + rr] = c.u;
            xs_h[(i * 4 + 3) * RPB + rr] = d.u;
        }
    }
    __syncthreads();

    floatx4 acc[8];
    #pragma unroll
    for (int m = 0; m < 8; ++m) acc[m] = (floatx4){0.f, 0.f, 0.f, 0.f};
    const int rb = wave * 128;
    const f16x2 z2 = {(f16)0, (f16)0};

    #pragma unroll 2
    for (int fi = 0; fi < FPB; ++fi) {
        F8 Bh, Bl, W, Bi;
        Bh.u = fB[fi * 128 + lane];          // ds_read_b128, 2-way alias free
        Bl.u = fB[fi * 128 + 64 + lane];
        W.u  = w1b1s[(fi * 4 + q) * 2];
        Bi.u = w1b1s[(fi * 4 + q) * 2 + 1];
        const float2 bw = bws[fi * 16 + n];

        #pragma unroll
        for (int m = 0; m < 8; ++m) {
            const unsigned short xu = xs_h[fi * RPB + rb + m * 16 + n];
            U1 xb; xb.u = ((unsigned)xu << 16) | xu;
            const f16x2 xp = xb.h;
            F8 A;
            #pragma unroll
            for (int tt = 0; tt < 4; ++tt) {
                f16x2 h = xp * W.h2[tt] + Bi.h2[tt];          // v_pk_fma_f16
                A.h2[tt] = __builtin_elementwise_max(h, z2);  // v_pk_max_f16
            }
            floatx4 c = {0.f, 0.f, 0.f, 0.f};
            c = __builtin_amdgcn_mfma_f32_16x16x32_f16(A.h8, Bh.h8, c, 0, 0, 0);
            c = __builtin_amdgcn_mfma_f32_16x16x32_f16(A.h8, Bl.h8, c, 0, 0, 0);
            #pragma unroll
            for (int r = 0; r < 4; ++r) {
                float u = c[r] + bw.x;
                u = u > 0.f ? u : 0.f;
                acc[m][r] = fmaf(u, bw.y, acc[m][r]);
            }
        }
    }

    float accb3 = 0.f;
    #pragma unroll
    for (int i = 0; i < FPB; ++i) accb3 += b3s[i];

    #pragma unroll
    for (int m = 0; m < 8; ++m) {
        #pragma unroll
        for (int r = 0; r < 4; ++r) {
            float v = acc[m][r];
            v += __shfl_xor(v, 1);
            v += __shfl_xor(v, 2);
            v += __shfl_xor(v, 4);
            v += __shfl_xor(v, 8);
            acc[m][r] = v;
        }
    }
    if (n == 0) {
        float* dst = part + (size_t)blockIdx.y * B_TOTAL + b0 + rb;
        #pragma unroll
        for (int m = 0; m < 8; ++m) {
            #pragma unroll
            for (int r = 0; r < 4; ++r)
                __hip_atomic_store(dst + m * 16 + q * 4 + r,
                                   acc[m][r] + accb3,
                                   __ATOMIC_RELAXED, __HIP_MEMORY_SCOPE_AGENT);
        }
    }
}

// Phase 2: each block finishes 16 output rows (sum NG groups + sigmoid).
__device__ __forceinline__ void nam_phase2(
    const float* __restrict__ part, float* __restrict__ out)
{
    __shared__ float red[256];
    const int t = threadIdx.x;
    const int flat = blockIdx.y * gridDim.x + blockIdx.x;   // 0..1023
    const int row = flat * 16 + (t & 15);
    const int g0 = (t >> 4) * 2;
    float p = __hip_atomic_load(part + (size_t)g0 * B_TOTAL + row,
                                __ATOMIC_RELAXED, __HIP_MEMORY_SCOPE_AGENT)
            + __hip_atomic_load(part + (size_t)(g0 + 1) * B_TOTAL + row,
                                __ATOMIC_RELAXED, __HIP_MEMORY_SCOPE_AGENT);
    red[t] = p;
    __syncthreads();
    if (t < 16) {
        float s = 0.f;
        #pragma unroll
        for (int i = 0; i < 16; ++i) s += red[i * 16 + t];
        out[flat * 16 + t] = 1.0f / (1.0f + expf(-s));
    }
}

__global__ __launch_bounds__(256, 4) void nam_coop(
    const float* __restrict__ x,  const float* __restrict__ W1,
    const float* __restrict__ b1, const float* __restrict__ W2,
    const float* __restrict__ b2, const float* __restrict__ W3,
    const float* __restrict__ b3, float* __restrict__ part,
    float* __restrict__ out)
{
    nam_phase1(x, W1, b1, W2, b2, W3, b3, part);
    cg::this_grid().sync();
    nam_phase2(part, out);
}

// Fallback (2 dispatches) if cooperative launch is unavailable.
__global__ __launch_bounds__(256, 4) void nam_p1(
    const float* __restrict__ x,  const float* __restrict__ W1,
    const float* __restrict__ b1, const float* __restrict__ W2,
    const float* __restrict__ b2, const float* __restrict__ W3,
    const float* __restrict__ b3, float* __restrict__ part)
{
    nam_phase1(x, W1, b1, W2, b2, W3, b3, part);
}

__global__ __launch_bounds__(256, 4) void nam_p2(
    const float* __restrict__ part, float* __restrict__ out)
{
    nam_phase2(part, out);
}

extern "C" void kernel_launch(void* const* d_in, const int* in_sizes, int n_in,
                              void* d_out, int out_size, void* d_ws, size_t ws_size,
                              hipStream_t stream) {
    const float* x  = (const float*)d_in[0];
    const float* W1 = (const float*)d_in[1];
    const float* b1 = (const float*)d_in[2];
    const float* W2 = (const float*)d_in[3];
    const float* b2 = (const float*)d_in[4];
    const float* W3 = (const float*)d_in[5];
    const float* b3 = (const float*)d_in[6];
    float* out = (float*)d_out;
    float* part = (float*)d_ws;    // [NG][B] = 2 MB, fully stored each launch

    dim3 grid(B_TOTAL / RPB, NG);  // (32, 32) = 1024 blocks = 4/CU co-resident
    dim3 block(256);

    void* args[] = {(void*)&x, (void*)&W1, (void*)&b1, (void*)&W2,
                    (void*)&b2, (void*)&W3, (void*)&b3, (void*)&part,
                    (void*)&out};
    hipError_t err = hipLaunchCooperativeKernel(
        (const void*)nam_coop, grid, block, args, 0, stream);
    if (err != hipSuccess) {
        nam_p1<<<grid, block, 0, stream>>>(x, W1, b1, W2, b2, W3, b3, part);
        nam_p2<<<grid, block, 0, stream>>>(part, out);
    }
}

// Round 11
// 93.471 us; speedup vs baseline: 2.3743x; 2.3743x over previous
//
#include <hip/hip_runtime.h>
#include <math.h>

#define B_TOTAL 16384
#define F_TOTAL 256
#define H1 32
#define H2 16
#define FPB 8      // features per block -> 32 feature groups
#define RPB 512    // rows per block (4 waves x 128 rows) -> 32 row blocks
#define NG 32      // feature groups

typedef _Float16 f16;
typedef __attribute__((ext_vector_type(2))) _Float16 f16x2;
typedef __attribute__((ext_vector_type(8))) _Float16 f16x8;
typedef __attribute__((ext_vector_type(4))) float floatx4;

union F8 { uint4 u; f16x2 h2[4]; f16x8 h8; };
union U1 { unsigned u; f16x2 h; };
union HU { f16 h; unsigned short u; };

// ---------- dispatch 1: inline pack (verified in R10) + K-loop ----------
// Block = 512 rows (4 waves x 128) x 8 features. Everything LDS-staged once;
// zero global ops and zero barriers in the K-loop. b2 rides the MFMA
// C-operand (saves the post-add); x stored pre-splatted as f16x2 bits
// (saves the per-m splat). Plain float4 partial stores (R8/R9-verified).
__global__ __launch_bounds__(256, 4) void nam_p1(
    const float* __restrict__ x,  const float* __restrict__ W1,
    const float* __restrict__ b1, const float* __restrict__ W2,
    const float* __restrict__ b2, const float* __restrict__ W3,
    const float* __restrict__ b3, float* __restrict__ part)
{
    __shared__ uint4 fB[FPB * 128];        // 16 KB: hi/lo B-frags
    __shared__ unsigned xs_u[FPB * RPB];   // 16 KB: x as splatted f16x2 bits
    __shared__ uint4 w1b1s[FPB * 4 * 2];   // 1 KB
    __shared__ float2 bws[FPB * 16];       // 1 KB
    __shared__ float b3s[FPB];

    const int t = threadIdx.x;
    const int lane = t & 63;
    const int wave = t >> 6;
    const int n = lane & 15, q = lane >> 4;
    const int b0 = blockIdx.x * RPB;
    const int f0 = blockIdx.y * FPB;

    // ---- inline pack: wave w packs features w*2, w*2+1 (R10-verified) ----
    #pragma unroll
    for (int k = 0; k < 2; ++k) {
        const int fi = wave * 2 + k;
        const int f = f0 + fi;
        F8 H, L;
        #pragma unroll
        for (int j = 0; j < 8; ++j) {
            float w = W2[(size_t)f * (H1 * H2) + (q * 8 + j) * H2 + n];
            f16 hi = (f16)w;
            H.h8[j] = hi;
            L.h8[j] = (f16)(w - (float)hi);
        }
        fB[fi * 128 + lane] = H.u;
        fB[fi * 128 + 64 + lane] = L.u;
        if (n == 0) {
            F8 A, Bb;
            #pragma unroll
            for (int j = 0; j < 8; ++j) {
                A.h8[j]  = (f16)W1[(size_t)f * H1 + q * 8 + j];
                Bb.h8[j] = (f16)b1[(size_t)f * H1 + q * 8 + j];
            }
            w1b1s[(fi * 4 + q) * 2]     = A.u;
            w1b1s[(fi * 4 + q) * 2 + 1] = Bb.u;
        }
        if (q == 0) {
            float2 e;
            e.x = b2[(size_t)f * H2 + n];
            e.y = W3[(size_t)f * H2 + n];
            bws[fi * 16 + n] = e;
        }
        if (lane == 0) b3s[fi] = b3[f];
    }
    // ---- stage x rows t and t+256 as pre-splatted f16x2 bits ----
    #pragma unroll
    for (int h = 0; h < 2; ++h) {
        const int rr = t + h * 256;
        const float4* xr = (const float4*)(x + (size_t)(b0 + rr) * F_TOTAL + f0);
        #pragma unroll
        for (int i = 0; i < 2; ++i) {
            float4 v = xr[i];
            HU a, b, c, d;
            a.h = (f16)v.x; b.h = (f16)v.y; c.h = (f16)v.z; d.h = (f16)v.w;
            xs_u[(i * 4 + 0) * RPB + rr] = ((unsigned)a.u << 16) | a.u;
            xs_u[(i * 4 + 1) * RPB + rr] = ((unsigned)b.u << 16) | b.u;
            xs_u[(i * 4 + 2) * RPB + rr] = ((unsigned)c.u << 16) | c.u;
            xs_u[(i * 4 + 3) * RPB + rr] = ((unsigned)d.u << 16) | d.u;
        }
    }
    __syncthreads();

    floatx4 acc[8];
    #pragma unroll
    for (int m = 0; m < 8; ++m) acc[m] = (floatx4){0.f, 0.f, 0.f, 0.f};
    const int rb = wave * 128;
    const f16x2 z2 = {(f16)0, (f16)0};

    #pragma unroll 2
    for (int fi = 0; fi < FPB; ++fi) {
        F8 Bh, Bl, W, Bi;
        Bh.u = fB[fi * 128 + lane];          // ds_read_b128, 2-way alias free
        Bl.u = fB[fi * 128 + 64 + lane];
        W.u  = w1b1s[(fi * 4 + q) * 2];
        Bi.u = w1b1s[(fi * 4 + q) * 2 + 1];
        const float2 bw = bws[fi * 16 + n];

        #pragma unroll
        for (int m = 0; m < 8; ++m) {
            U1 xb; xb.u = xs_u[fi * RPB + rb + m * 16 + n];  // ds_read_b32
            const f16x2 xp = xb.h;
            F8 A;
            #pragma unroll
            for (int tt = 0; tt < 4; ++tt) {
                f16x2 h = xp * W.h2[tt] + Bi.h2[tt];          // v_pk_fma_f16
                A.h2[tt] = __builtin_elementwise_max(h, z2);  // v_pk_max_f16
            }
            floatx4 c = {bw.x, bw.x, bw.x, bw.x};   // b2 folded into C-operand
            c = __builtin_amdgcn_mfma_f32_16x16x32_f16(A.h8, Bh.h8, c, 0, 0, 0);
            c = __builtin_amdgcn_mfma_f32_16x16x32_f16(A.h8, Bl.h8, c, 0, 0, 0);
            #pragma unroll
            for (int r = 0; r < 4; ++r) {
                float u = c[r] > 0.f ? c[r] : 0.f;
                acc[m][r] = fmaf(u, bw.y, acc[m][r]);
            }
        }
    }

    float accb3 = 0.f;
    #pragma unroll
    for (int i = 0; i < FPB; ++i) accb3 += b3s[i];

    // reduce over the 16 columns (n) within each 16-lane group
    #pragma unroll
    for (int m = 0; m < 8; ++m) {
        #pragma unroll
        for (int r = 0; r < 4; ++r) {
            float v = acc[m][r];
            v += __shfl_xor(v, 1);
            v += __shfl_xor(v, 2);
            v += __shfl_xor(v, 4);
            v += __shfl_xor(v, 8);
            acc[m][r] = v;
        }
    }
    if (n == 0) {
        // wave covers rows b0+rb .. b0+rb+127; tile m rows m*16+q*4..+3
        float* dst = part + (size_t)blockIdx.y * B_TOTAL + b0 + rb;
        #pragma unroll
        for (int m = 0; m < 8; ++m) {
            float4 o;
            o.x = acc[m][0] + accb3; o.y = acc[m][1] + accb3;
            o.z = acc[m][2] + accb3; o.w = acc[m][3] + accb3;
            *(float4*)(dst + m * 16 + q * 4) = o;
        }
    }
}

// ---------- dispatch 2: sum 32 groups + sigmoid ----------
__global__ __launch_bounds__(256) void nam_p2(
    const float* __restrict__ part, float* __restrict__ out)
{
    const int b = blockIdx.x * 256 + threadIdx.x;
    float s = 0.f;
    #pragma unroll
    for (int g = 0; g < NG; ++g) s += part[(size_t)g * B_TOTAL + b];
    out[b] = 1.0f / (1.0f + expf(-s));
}

extern "C" void kernel_launch(void* const* d_in, const int* in_sizes, int n_in,
                              void* d_out, int out_size, void* d_ws, size_t ws_size,
                              hipStream_t stream) {
    const float* x  = (const float*)d_in[0];
    const float* W1 = (const float*)d_in[1];
    const float* b1 = (const float*)d_in[2];
    const float* W2 = (const float*)d_in[3];
    const float* b2 = (const float*)d_in[4];
    const float* W3 = (const float*)d_in[5];
    const float* b3 = (const float*)d_in[6];
    float* out = (float*)d_out;
    float* part = (float*)d_ws;   // [NG][B] = 2 MB, every slot stored each launch

    dim3 grid(B_TOTAL / RPB, NG);   // (32, 32) = 1024 blocks = 4/CU
    nam_p1<<<grid, 256, 0, stream>>>(x, W1, b1, W2, b2, W3, b3, part);
    nam_p2<<<B_TOTAL / 256, 256, 0, stream>>>(part, out);
}